// Round 1
// baseline (60.676 us; speedup 1.0000x reference)
//
#include <hip/hip_runtime.h>
#include <math.h>

#define MASKN 64
#define NPTS 32
#define INV_STRIDE 0.0625f          // 1/16, exact power of two
#define NEG_INV_TWO_SIGMA2 (-1.0f / 882.0f)   // 2*21*21

__global__ __launch_bounds__(256) void fused_masks_kernel(
    const float* __restrict__ boxes,      // (B,4)
    const float* __restrict__ pts,        // (B,32,2)
    float* __restrict__ out_bbox,         // (B,64,64)
    float* __restrict__ out_point)        // (B,64,64)
{
    const int b = blockIdx.x;
    const int t = threadIdx.x;

    __shared__ float rf[NPTS][MASKN];   // valid ? exp(-(i-py)^2/882) : 0
    __shared__ float cf[NPTS][MASKN];   // valid ? exp(-(j-px)^2/882) : 0
    __shared__ int   s_px[NPTS];
    __shared__ int   s_py[NPTS];
    __shared__ int   s_valid[NPTS];
    __shared__ int   s_box[4];          // xmin_i, xmax_i, ymin_i, ymax_i

    if (t < NPTS) {
        float x = pts[((size_t)b * NPTS + t) * 2 + 0];
        float y = pts[((size_t)b * NPTS + t) * 2 + 1];
        int px = (int)floorf(x * INV_STRIDE);
        int py = (int)floorf(y * INV_STRIDE);
        s_px[t] = px;
        s_py[t] = py;
        s_valid[t] = (px >= 0) && (py >= 0) && (px < MASKN) && (py < MASKN);
    }
    if (t == 0) {
        float x0 = boxes[b * 4 + 0], y0 = boxes[b * 4 + 1];
        float x1 = boxes[b * 4 + 2], y1 = boxes[b * 4 + 3];
        float xmn = fminf(x0, x1), xmx = fmaxf(x0, x1);
        float ymn = fminf(y0, y1), ymx = fmaxf(y0, y1);
        int xmin_i = max((int)floorf(xmn * INV_STRIDE), 0);
        int xmax_i = min((int)floorf(xmx * INV_STRIDE) + 1, MASKN);
        int ymin_i = max((int)floorf(ymn * INV_STRIDE), 0);
        int ymax_i = min((int)floorf(ymx * INV_STRIDE) + 1, MASKN);
        s_box[0] = xmin_i; s_box[1] = xmax_i;
        s_box[2] = ymin_i; s_box[3] = ymax_i;
    }
    __syncthreads();

    // Fill factor tables: 32*64 entries each, 256 threads -> 8 (p,i) pairs/thread
    for (int e = t; e < NPTS * MASKN; e += 256) {
        int p = e >> 6, i = e & 63;
        float v = s_valid[p] ? 1.0f : 0.0f;
        float dy = (float)(i - s_py[p]);
        float dx = (float)(i - s_px[p]);
        // invalid: v=0; exp underflows to 0 for huge |d| so no NaN (exp(-inf)=0)
        rf[p][i] = v * __expf(dy * dy * NEG_INV_TWO_SIGMA2);
        cf[p][i] = v * __expf(dx * dx * NEG_INV_TWO_SIGMA2);
    }
    __syncthreads();

    const int xmin_i = s_box[0], xmax_i = s_box[1];
    const int ymin_i = s_box[2], ymax_i = s_box[3];

    const int j0 = (t & 15) * 4;   // column base, shared by this thread's 4 groups
    const int r0 = t >> 4;         // base row; rows are r0 + 16*k, k=0..3

    float4 m[4];
    #pragma unroll
    for (int k = 0; k < 4; ++k) m[k] = make_float4(0.f, 0.f, 0.f, 0.f);

    for (int p = 0; p < NPTS; ++p) {
        const float4 c = *(const float4*)&cf[p][j0];   // one ds_read_b128
        #pragma unroll
        for (int k = 0; k < 4; ++k) {
            const float ry = rf[p][r0 + 16 * k];       // broadcast b32
            m[k].x = fmaxf(m[k].x, ry * c.x);
            m[k].y = fmaxf(m[k].y, ry * c.y);
            m[k].z = fmaxf(m[k].z, ry * c.z);
            m[k].w = fmaxf(m[k].w, ry * c.w);
        }
    }

    const size_t base = (size_t)b * (MASKN * MASKN);
    const float bx0 = (j0 + 0 >= xmin_i && j0 + 0 < xmax_i) ? 1.0f : 0.0f;
    const float bx1 = (j0 + 1 >= xmin_i && j0 + 1 < xmax_i) ? 1.0f : 0.0f;
    const float bx2 = (j0 + 2 >= xmin_i && j0 + 2 < xmax_i) ? 1.0f : 0.0f;
    const float bx3 = (j0 + 3 >= xmin_i && j0 + 3 < xmax_i) ? 1.0f : 0.0f;

    #pragma unroll
    for (int k = 0; k < 4; ++k) {
        const int i = r0 + 16 * k;
        const int idx = i * MASKN + j0;
        *(float4*)&out_point[base + idx] = m[k];
        const float iny = (i >= ymin_i && i < ymax_i) ? 1.0f : 0.0f;
        float4 bb = make_float4(iny * bx0, iny * bx1, iny * bx2, iny * bx3);
        *(float4*)&out_bbox[base + idx] = bb;
    }
}

extern "C" void kernel_launch(void* const* d_in, const int* in_sizes, int n_in,
                              void* d_out, int out_size, void* d_ws, size_t ws_size,
                              hipStream_t stream) {
    const float* boxes = (const float*)d_in[0];
    const float* pts   = (const float*)d_in[1];
    float* out = (float*)d_out;

    const int B = in_sizes[0] / 4;                 // 256
    float* out_bbox  = out;                        // (B,64,64)
    float* out_point = out + (size_t)B * MASKN * MASKN;

    fused_masks_kernel<<<dim3(B), dim3(256), 0, stream>>>(boxes, pts, out_bbox, out_point);
}